// Round 8
// baseline (700.729 us; speedup 1.0000x reference)
//
#include <hip/hip_runtime.h>
#include <hip/hip_bf16.h>
#include <math.h>

// UHG InfoNCE: fused distance/similarity matrix + streaming row-logsumexp.
// N=8192, D=64 fp32. Mandatory writes ~537MB -> ~86us floor.
// r4: bit-exact, main ~300us. r6: launch_bounds(256,4) spill disaster (16.3ms).
// r7: double-buffered LDS-K, main ~220us — still 2.5x over write floor; the
//     16 per-step barrier+vmcnt drains and 64 ds_read_b32/step are the stall.
// r8: K via L2 (no LDS-K, no staging, ZERO main-loop barriers). Block =
//     32 rows x 1024 cols; thread = 8 rows x 4 strided cols; K read with
//     coalesced global loads (2.15GB L2 total, XCD-local Kt slices). Q in
//     LDS (9KB) staged once. Numerically identical to r7 (absmax=0.0).
//
// Analytic simplifications (exact in fp32, proven absmax=0.0 in r4/r6/r7):
//  1. pos_sim cancels: per_row = -sims[i,0] + logsumexp_j(sims[i,j]).
//  2. max(ratio, 1.0+1e-9) == max(ratio, 1.0f) in fp32; ratio<1 for ~all
//     pairs -> dist=0, sim=0 exactly. Classify by inner^2 > 0.9999*denom2;
//     borderline lanes take the exact div/clamp path.
//  3. Row max is exactly 0 -> accumulate S = sum(exp(sim)) with m=0 fixed.

#define NN 8192
#define DD 64

static constexpr float EPSV      = 1e-9f;
static constexpr float NEG_INV_T = -1.0f / 0.07f;

// ---------------------------------------------------------------------------
// Kernel 1: Kt[d][j] = K[j][d], d==63 (timelike) negated.
// ---------------------------------------------------------------------------
__global__ __launch_bounds__(256) void uhg_transpose_negate(
    const float* __restrict__ K, float* __restrict__ Kt)
{
    __shared__ float T[64][65];
    const int tid = threadIdx.x;
    const int j0  = blockIdx.x * 64;
    {
        const int j = tid >> 2;
        const int c = (tid & 3) * 16;
        const float* src = K + (size_t)(j0 + j) * DD + c;
        #pragma unroll
        for (int u = 0; u < 4; ++u) {
            const float4 v = *reinterpret_cast<const float4*>(src + 4 * u);
            T[j][c + 4*u + 0] = v.x;
            T[j][c + 4*u + 1] = v.y;
            T[j][c + 4*u + 2] = v.z;
            T[j][c + 4*u + 3] = v.w;
        }
    }
    __syncthreads();
    {
        const int d = tid >> 2;
        const int c = (tid & 3) * 16;
        const float sgn = (d == 63) ? -1.0f : 1.0f;
        float* dst = Kt + (size_t)d * NN + j0 + c;
        #pragma unroll
        for (int u = 0; u < 4; ++u) {
            float4 v;
            v.x = sgn * T[c + 4*u + 0][d];
            v.y = sgn * T[c + 4*u + 1][d];
            v.z = sgn * T[c + 4*u + 2][d];
            v.w = sgn * T[c + 4*u + 3][d];
            *reinterpret_cast<float4*>(dst + 4 * u) = v;
        }
    }
}

// ---------------------------------------------------------------------------
// Kernel 2: Minkowski self-inner products qq[i], kk[j].
// ---------------------------------------------------------------------------
__global__ __launch_bounds__(256) void uhg_qqkk(
    const float* __restrict__ Q, const float* __restrict__ K,
    float* __restrict__ qq, float* __restrict__ kk)
{
    const int i = blockIdx.x * 256 + threadIdx.x;
    const bool isQ = (i < NN);
    const int r = isQ ? i : (i - NN);
    const float* src = (isQ ? Q : K) + (size_t)r * DD;
    float acc = 0.0f;
    #pragma unroll
    for (int c = 0; c < 15; ++c) {
        const float4 v = *reinterpret_cast<const float4*>(src + 4 * c);
        acc += v.x*v.x + v.y*v.y + v.z*v.z + v.w*v.w;
    }
    const float4 v = *reinterpret_cast<const float4*>(src + 60);
    acc += v.x*v.x + v.y*v.y + v.z*v.z;
    acc -= v.w*v.w;
    (isQ ? qq : kk)[r] = acc;
}

// ---------------------------------------------------------------------------
// Kernel 3: main fused kernel — barrier-free K path.
// Grid 2048 x 256 thr. Block (rblk, cs) owns rows [32*rblk,+32) x cols
// [1024*cs,+1024), cs in 0..7 (cs aligns with XCD round-robin -> each XCD
// reads only its 256KB Kt slice from its own L2). 4 tiles of 256 cols.
// Thread: 8 rows x 4 strided cols; K read directly from L2 (coalesced
// global_load_dword, saddr-form), Q broadcast from LDS. One barrier total.
// ---------------------------------------------------------------------------
__global__ __launch_bounds__(256) void uhg_main(
    const float* __restrict__ Q, const float* __restrict__ Kt,
    const float* __restrict__ qq, const float* __restrict__ kk,
    float* __restrict__ out_sims, float* __restrict__ out_dist,
    float* __restrict__ Spart, float* __restrict__ sim0part)
{
    constexpr int TM = 32;     // rows per block
    constexpr int CB = 1024;   // cols per block
    constexpr int TN = 256;    // cols per tile

    __shared__ float Qs[DD][36];      // dim-major Q tile (pad 36; 16B rows)

    const int tid   = threadIdx.x;
    const int tx    = tid & 63;
    const int ty    = tid >> 6;       // wave id (uniform)
    const int cs    = blockIdx.x & 7; // column slice (8 x 1024 = full N)
    const int row0  = (blockIdx.x >> 3) * TM;
    const int cbase = cs * CB;
    const int wrow  = 8 * ty;         // wave's first row within tile

    // ---- stage Q tile (once): 32 rows x 64 dims, dim-major ----
    {
        const int r  = tid >> 3;      // 0..31
        const int dc = (tid & 7) * 8; // 0..56
        const float* src = Q + (size_t)(row0 + r) * DD + dc;
        const float4 v0 = *reinterpret_cast<const float4*>(src);
        const float4 v1 = *reinterpret_cast<const float4*>(src + 4);
        Qs[dc + 0][r] = v0.x;  Qs[dc + 1][r] = v0.y;
        Qs[dc + 2][r] = v0.z;  Qs[dc + 3][r] = v0.w;
        Qs[dc + 4][r] = v1.x;  Qs[dc + 5][r] = v1.y;
        Qs[dc + 6][r] = v1.z;  Qs[dc + 7][r] = v1.w;
    }

    float rq[8];
    {
        const float4 a = *reinterpret_cast<const float4*>(qq + row0 + wrow);
        const float4 b = *reinterpret_cast<const float4*>(qq + row0 + wrow + 4);
        rq[0]=a.x; rq[1]=a.y; rq[2]=a.z; rq[3]=a.w;
        rq[4]=b.x; rq[5]=b.y; rq[6]=b.z; rq[7]=b.w;
    }

    float s[8]     = {0,0,0,0,0,0,0,0};   // S = sum(exp(sim)), m fixed at 0
    float sim0r[8] = {0,0,0,0,0,0,0,0};

    __syncthreads();                  // Qs ready — the ONLY barrier

    for (int t = 0; t < CB / TN; ++t) {
        const int c0 = cbase + t * TN;
        const float* kp = Kt + c0 + tx;   // lane-coalesced K base
        float acc[8][4] = {};

        #pragma unroll 8
        for (int d = 0; d < DD; ++d) {
            const float4 qv0 = *reinterpret_cast<const float4*>(&Qs[d][wrow]);
            const float4 qv1 = *reinterpret_cast<const float4*>(&Qs[d][wrow + 4]);
            const float qa[8] = {qv0.x, qv0.y, qv0.z, qv0.w,
                                 qv1.x, qv1.y, qv1.z, qv1.w};
            const size_t off = (size_t)d * NN;
            float kv[4];
            kv[0] = kp[off];
            kv[1] = kp[off + 64];
            kv[2] = kp[off + 128];
            kv[3] = kp[off + 192];
            #pragma unroll
            for (int rr = 0; rr < 8; ++rr)
                #pragma unroll
                for (int i = 0; i < 4; ++i)
                    acc[rr][i] = fmaf(qa[rr], kv[i], acc[rr][i]);
        }

        // ---- epilogue: clamp-classified, bit-exact (r4/r7-verified) ----
        float rk[4];
        rk[0] = kk[c0 + tx];
        rk[1] = kk[c0 + tx + 64];
        rk[2] = kk[c0 + tx + 128];
        rk[3] = kk[c0 + tx + 192];

        #pragma unroll
        for (int rr = 0; rr < 8; ++rr) {
            const size_t rowoff = (size_t)(row0 + wrow + rr) * NN + c0 + tx;
            float* psr = out_sims + rowoff;
            float* pdr = out_dist + rowoff;
            #pragma unroll
            for (int i = 0; i < 4; ++i) {
                const float inner = acc[rr][i];
                const float dd2 = fmaxf(fabsf(rq[rr] * rk[i]), EPSV);
                float dist = 0.0f, sim = 0.0f, e = 1.0f;
                if (inner * inner > dd2 * 0.9999f) {  // rare slow path
                    const float ratio = fmaxf(fabsf(inner) / sqrtf(dd2), 1.0f);
                    dist = __logf(ratio + sqrtf(fmaf(ratio, ratio, -1.0f)));
                    sim  = dist * NEG_INV_T;
                    e    = __expf(sim);
                }
                __builtin_nontemporal_store(dist, pdr + 64 * i);
                __builtin_nontemporal_store(sim,  psr + 64 * i);
                if (cs == 0 && t == 0 && i == 0 && tx == 0) sim0r[rr] = sim;
                s[rr] += e;
            }
        }
    }

    // ---- reduce S across the 64 lanes of each row ----
    #pragma unroll
    for (int rr = 0; rr < 8; ++rr) {
        float v = s[rr];
        #pragma unroll
        for (int mask = 32; mask > 0; mask >>= 1)
            v += __shfl_xor(v, mask, 64);
        s[rr] = v;
    }
    if (tx == 0) {
        #pragma unroll
        for (int rr = 0; rr < 8; ++rr) {
            const int row = row0 + wrow + rr;
            Spart[cs * NN + row] = s[rr];
            if (cs == 0) sim0part[row] = sim0r[rr];
        }
    }
}

// ---------------------------------------------------------------------------
// Kernel 4: loss = sum_i(-sim0_i + log(sum_{cs} Spart[cs][i])) / N.
// ---------------------------------------------------------------------------
__global__ __launch_bounds__(256) void uhg_finalize(
    const float* __restrict__ Spart, const float* __restrict__ sim0part,
    float* __restrict__ out)
{
    __shared__ float red[256];
    const int tid = threadIdx.x;
    float a = 0.0f;
    for (int r = tid; r < NN; r += 256) {
        float S = 0.0f;
        #pragma unroll
        for (int q = 0; q < 8; ++q) S += Spart[q * NN + r];
        a += -sim0part[r] + logf(S);
    }
    red[tid] = a;
    __syncthreads();
    for (int off = 128; off > 0; off >>= 1) {
        if (tid < off) red[tid] += red[tid + off];
        __syncthreads();
    }
    if (tid == 0) out[0] = red[0] / (float)NN;
}

// ---------------------------------------------------------------------------
extern "C" void kernel_launch(void* const* d_in, const int* in_sizes, int n_in,
                              void* d_out, int out_size, void* d_ws, size_t ws_size,
                              hipStream_t stream)
{
    const float* Q = (const float*)d_in[0];
    const float* K = (const float*)d_in[1];
    // d_in[2] (positive_indices) cancels analytically -> unused.

    float* out      = (float*)d_out;
    float* out_sims = out + 1;
    float* out_dist = out + 1 + (size_t)NN * NN;

    float* w        = (float*)d_ws;       // ~2.5MB of ws used
    float* Kt       = w;                  // 64*8192 = 524288
    float* qq       = w + 524288;         // 8192
    float* kk       = w + 532480;         // 8192
    float* Spart    = w + 540672;         // 8*8192 = 65536
    float* sim0part = w + 606208;         // 8192

    uhg_transpose_negate<<<NN / 64, 256, 0, stream>>>(K, Kt);
    uhg_qqkk<<<2 * NN / 256, 256, 0, stream>>>(Q, K, qq, kk);
    uhg_main<<<2048, 256, 0, stream>>>(Q, Kt, qq, kk, out_sims, out_dist,
                                       Spart, sim0part);
    uhg_finalize<<<1, 256, 0, stream>>>(Spart, sim0part, out);
}

// Round 9
// 695.177 us; speedup vs baseline: 1.0080x; 1.0080x over previous
//
#include <hip/hip_runtime.h>
#include <hip/hip_bf16.h>
#include <math.h>

// UHG InfoNCE: fused distance/similarity matrix + streaming row-logsumexp.
// N=8192, D=64 fp32. Mandatory writes ~537MB -> ~86us floor.
// r4: bit-exact, main ~300us. r6: forced-occupancy spill disaster (16.3ms).
// r7: LDS double-buffer, main ~220us. r8: K-via-L2, main ~253us.
// Post-mortem r7/r8: wave-uniform Q broadcasts through the SHARED per-CU LDS
// unit (2x ds_read_b128 per d per wave for 32B of data) serialize against
// FMAs; LDS is the wrong pipe for rank-1 broadcasts.
// r9: NO LDS, NO barriers. Thread tile 8x8 (halves per-FMA overhead). Q read
// via readfirstlane-uniform pointer into dim-major Qt (L1 broadcast / s_load).
// K via L2 (one bumped pointer, 8 imm offsets). sim0 read back from out_sims
// in finalize (saves regs + hot-loop branch).
//
// Analytic simplifications (exact in fp32, proven absmax=0.0 r4/r6/r7/r8):
//  1. pos_sim cancels: per_row = -sims[i,0] + logsumexp_j(sims[i,j]).
//  2. max(ratio, 1.0+1e-9) == max(ratio, 1.0f) in fp32; ratio<1 for ~all
//     pairs -> dist=0, sim=0 exactly. Classify by inner^2 > 0.9999*denom2;
//     borderline lanes take the exact div/clamp path.
//  3. Row max is exactly 0 -> accumulate S = sum(exp(sim)) with m=0 fixed.

#define NN 8192
#define DD 64

static constexpr float EPSV      = 1e-9f;
static constexpr float NEG_INV_T = -1.0f / 0.07f;

// ---------------------------------------------------------------------------
// Kernel 1: dim-major transposes. blocks [0,128): Kt[d][j] = K[j][d] with
// d==63 negated (folds Minkowski signature); blocks [128,256): Qt[d][j]=Q[j][d].
// ---------------------------------------------------------------------------
__global__ __launch_bounds__(256) void uhg_transpose(
    const float* __restrict__ Q, const float* __restrict__ K,
    float* __restrict__ Qt, float* __restrict__ Kt)
{
    __shared__ float T[64][65];
    const int tid = threadIdx.x;
    const bool isK = blockIdx.x < (NN / 64);
    const int j0  = (isK ? blockIdx.x : blockIdx.x - NN / 64) * 64;
    const float* src0 = isK ? K : Q;
    float* dst0 = isK ? Kt : Qt;
    {
        const int j = tid >> 2;
        const int c = (tid & 3) * 16;
        const float* src = src0 + (size_t)(j0 + j) * DD + c;
        #pragma unroll
        for (int u = 0; u < 4; ++u) {
            const float4 v = *reinterpret_cast<const float4*>(src + 4 * u);
            T[j][c + 4*u + 0] = v.x;
            T[j][c + 4*u + 1] = v.y;
            T[j][c + 4*u + 2] = v.z;
            T[j][c + 4*u + 3] = v.w;
        }
    }
    __syncthreads();
    {
        const int d = tid >> 2;
        const int c = (tid & 3) * 16;
        const float sgn = (isK && d == 63) ? -1.0f : 1.0f;
        float* dst = dst0 + (size_t)d * NN + j0 + c;
        #pragma unroll
        for (int u = 0; u < 4; ++u) {
            float4 v;
            v.x = sgn * T[c + 4*u + 0][d];
            v.y = sgn * T[c + 4*u + 1][d];
            v.z = sgn * T[c + 4*u + 2][d];
            v.w = sgn * T[c + 4*u + 3][d];
            *reinterpret_cast<float4*>(dst + 4 * u) = v;
        }
    }
}

// ---------------------------------------------------------------------------
// Kernel 2: Minkowski self-inner products qq[i], kk[j].
// ---------------------------------------------------------------------------
__global__ __launch_bounds__(256) void uhg_qqkk(
    const float* __restrict__ Q, const float* __restrict__ K,
    float* __restrict__ qq, float* __restrict__ kk)
{
    const int i = blockIdx.x * 256 + threadIdx.x;
    const bool isQ = (i < NN);
    const int r = isQ ? i : (i - NN);
    const float* src = (isQ ? Q : K) + (size_t)r * DD;
    float acc = 0.0f;
    #pragma unroll
    for (int c = 0; c < 15; ++c) {
        const float4 v = *reinterpret_cast<const float4*>(src + 4 * c);
        acc += v.x*v.x + v.y*v.y + v.z*v.z + v.w*v.w;
    }
    const float4 v = *reinterpret_cast<const float4*>(src + 60);
    acc += v.x*v.x + v.y*v.y + v.z*v.z;
    acc -= v.w*v.w;
    (isQ ? qq : kk)[r] = acc;
}

// ---------------------------------------------------------------------------
// Kernel 3: main fused kernel — LDS-free, barrier-free.
// Grid 4096 x 256 thr = 256 rowblocks x 16 col-slices. Block: 32 rows x 512
// cols. Thread: 8 rows x 8 strided cols (acc 8x8). Q: uniform global loads
// (wave-broadcast via L1/s_load) from Qt. K: per-lane coalesced loads from
// L2-resident Kt. Epilogue: clamp-classified (bit-exact), scalar nontemporal
// stores, butterfly S reduction, per-slice S partials.
// ---------------------------------------------------------------------------
__global__ __launch_bounds__(256) void uhg_main(
    const float* __restrict__ Qt, const float* __restrict__ Kt,
    const float* __restrict__ qq, const float* __restrict__ kk,
    float* __restrict__ out_sims, float* __restrict__ out_dist,
    float* __restrict__ Spart)
{
    const int tid   = threadIdx.x;
    const int tx    = tid & 63;
    const int ty    = tid >> 6;            // wave id (uniform)
    const int slice = blockIdx.x & 15;     // 16 col-slices x 512
    const int row0  = (blockIdx.x >> 4) * 32;
    const int c0    = slice * 512;
    // wave's first global row; readfirstlane pins it uniform -> scalar loads
    const int wrow  = __builtin_amdgcn_readfirstlane(row0 + 8 * ty);

    const float* qp = Qt + wrow;           // uniform: Qt[d][wrow..wrow+7]
    const float* kp = Kt + c0 + tx;        // per-lane: Kt[d][c0+tx+64i]

    float acc[8][8] = {};

    #pragma unroll 4
    for (int d = 0; d < DD; ++d) {
        const size_t off = (size_t)d * NN;
        const float4 qv0 = *reinterpret_cast<const float4*>(qp + off);
        const float4 qv1 = *reinterpret_cast<const float4*>(qp + off + 4);
        const float qa[8] = {qv0.x, qv0.y, qv0.z, qv0.w,
                             qv1.x, qv1.y, qv1.z, qv1.w};
        float kv[8];
        #pragma unroll
        for (int i = 0; i < 8; ++i) kv[i] = kp[off + 64 * i];
        #pragma unroll
        for (int rr = 0; rr < 8; ++rr)
            #pragma unroll
            for (int i = 0; i < 8; ++i)
                acc[rr][i] = fmaf(qa[rr], kv[i], acc[rr][i]);
    }

    // ---- epilogue: clamp-classified distances/sims + stores + S ----
    float rq[8];
    {
        const float4 a = *reinterpret_cast<const float4*>(qq + wrow);
        const float4 b = *reinterpret_cast<const float4*>(qq + wrow + 4);
        rq[0]=a.x; rq[1]=a.y; rq[2]=a.z; rq[3]=a.w;
        rq[4]=b.x; rq[5]=b.y; rq[6]=b.z; rq[7]=b.w;
    }
    float rk[8];
    #pragma unroll
    for (int i = 0; i < 8; ++i) rk[i] = kk[c0 + tx + 64 * i];

    float s[8];
    #pragma unroll
    for (int rr = 0; rr < 8; ++rr) {
        const size_t rowoff = (size_t)(wrow + rr) * NN + c0 + tx;
        float* psr = out_sims + rowoff;
        float* pdr = out_dist + rowoff;
        float sr = 0.0f;
        #pragma unroll
        for (int i = 0; i < 8; ++i) {
            const float inner = acc[rr][i];
            const float dd2 = fmaxf(fabsf(rq[rr] * rk[i]), EPSV);
            float dist = 0.0f, sim = 0.0f, e = 1.0f;
            if (inner * inner > dd2 * 0.9999f) {   // rare slow path
                const float ratio = fmaxf(fabsf(inner) / sqrtf(dd2), 1.0f);
                dist = __logf(ratio + sqrtf(fmaf(ratio, ratio, -1.0f)));
                sim  = dist * NEG_INV_T;
                e    = __expf(sim);
            }
            __builtin_nontemporal_store(dist, pdr + 64 * i);
            __builtin_nontemporal_store(sim,  psr + 64 * i);
            sr += e;
        }
        s[rr] = sr;
    }

    // ---- butterfly-reduce S across the 64 lanes of each row ----
    #pragma unroll
    for (int rr = 0; rr < 8; ++rr) {
        float v = s[rr];
        #pragma unroll
        for (int mask = 32; mask > 0; mask >>= 1)
            v += __shfl_xor(v, mask, 64);
        s[rr] = v;
    }
    if (tx == 0) {
        #pragma unroll
        for (int rr = 0; rr < 8; ++rr)
            Spart[(size_t)slice * NN + wrow + rr] = s[rr];
    }
}

// ---------------------------------------------------------------------------
// Kernel 4: loss = sum_i(-sims[i][0] + log(sum_{16} Spart)) / N.
// sims[i][0] read back from out_sims (written by slice-0 blocks).
// ---------------------------------------------------------------------------
__global__ __launch_bounds__(256) void uhg_finalize(
    const float* __restrict__ Spart, const float* __restrict__ out_sims,
    float* __restrict__ out)
{
    __shared__ float red[256];
    const int tid = threadIdx.x;
    float a = 0.0f;
    for (int r = tid; r < NN; r += 256) {
        float S = 0.0f;
        #pragma unroll
        for (int q = 0; q < 16; ++q) S += Spart[(size_t)q * NN + r];
        a += -out_sims[(size_t)r * NN] + logf(S);
    }
    red[tid] = a;
    __syncthreads();
    for (int off = 128; off > 0; off >>= 1) {
        if (tid < off) red[tid] += red[tid + off];
        __syncthreads();
    }
    if (tid == 0) out[0] = red[0] / (float)NN;
}

// ---------------------------------------------------------------------------
extern "C" void kernel_launch(void* const* d_in, const int* in_sizes, int n_in,
                              void* d_out, int out_size, void* d_ws, size_t ws_size,
                              hipStream_t stream)
{
    const float* Q = (const float*)d_in[0];
    const float* K = (const float*)d_in[1];
    // d_in[2] (positive_indices) cancels analytically -> unused.

    float* out      = (float*)d_out;
    float* out_sims = out + 1;
    float* out_dist = out + 1 + (size_t)NN * NN;

    float* w     = (float*)d_ws;          // ~4.8MB of ws used (ws is ~2GB)
    float* Kt    = w;                     // 64*8192 = 524288
    float* Qt    = w + 524288;            // 524288
    float* qq    = w + 1048576;           // 8192
    float* kk    = w + 1056768;           // 8192
    float* Spart = w + 1064960;           // 16*8192 = 131072

    uhg_transpose<<<2 * NN / 64, 256, 0, stream>>>(Q, K, Qt, Kt);
    uhg_qqkk<<<2 * NN / 256, 256, 0, stream>>>(Q, K, qq, kk);
    uhg_main<<<4096, 256, 0, stream>>>(Qt, Kt, qq, kk, out_sims, out_dist,
                                       Spart);
    uhg_finalize<<<1, 256, 0, stream>>>(Spart, out_sims, out);
}